// Round 17
// baseline (34.904 us; speedup 1.0000x reference)
//
#include <hip/hip_runtime.h>

typedef float  f32x4 __attribute__((ext_vector_type(4)));
typedef short  s16x8 __attribute__((ext_vector_type(8)));
typedef _Float16 h2 __attribute__((ext_vector_type(2)));
typedef unsigned short u16;
typedef u16 u16x4 __attribute__((ext_vector_type(4)));

#define N_DIMS 1024
#define N_OSC  352
#define N_PH   96
#define BATCH  4096
#define EPSV   1e-6f
#define INV2PI 0.15915494309189535f

__device__ __forceinline__ u16 f2bf(float f){
  unsigned u = __builtin_bit_cast(unsigned, f);
  u += 0x7FFFu + ((u >> 16) & 1u);   // RNE
  return (u16)(u >> 16);
}
__device__ __forceinline__ unsigned pkbf(float a, float b){
  unsigned r; asm("v_cvt_pk_bf16_f32 %0, %1, %2" : "=v"(r) : "v"(a), "v"(b)); return r;
}
__device__ __forceinline__ s16x8 mk8(f32x4 a, f32x4 b){
  uint4 u; u.x = pkbf(a[0],a[1]); u.y = pkbf(a[2],a[3]);
  u.z = pkbf(b[0],b[1]); u.w = pkbf(b[2],b[3]);
  return __builtin_bit_cast(s16x8, u);
}
__device__ __forceinline__ void gload16(const u16* g, u16* l){
  __builtin_amdgcn_global_load_lds(
      (const __attribute__((address_space(1))) unsigned int*)(g),
      (__attribute__((address_space(3))) unsigned int*)(l), 16, 0, 0);
}
__device__ __forceinline__ void gload16f(const float* g, float* l){
  __builtin_amdgcn_global_load_lds(
      (const __attribute__((address_space(1))) unsigned int*)(g),
      (__attribute__((address_space(3))) unsigned int*)(l), 16, 0, 0);
}

// ---- iter helpers (v2) ----
__device__ __forceinline__ int ibc(h2 v){ return __builtin_bit_cast(int, v); }
__device__ __forceinline__ h2  hbc(int v){ return __builtin_bit_cast(h2, v); }
__device__ __forceinline__ h2 rowsum16(h2 x){
  int v = ibc(x);
  v = ibc(hbc(v) + hbc(__builtin_amdgcn_mov_dpp(v, 0x121, 0xF, 0xF, true))); // ror1
  v = ibc(hbc(v) + hbc(__builtin_amdgcn_mov_dpp(v, 0x122, 0xF, 0xF, true))); // ror2
  v = ibc(hbc(v) + hbc(__builtin_amdgcn_mov_dpp(v, 0x124, 0xF, 0xF, true))); // ror4
  v = ibc(hbc(v) + hbc(__builtin_amdgcn_mov_dpp(v, 0x128, 0xF, 0xF, true))); // ror8
  return hbc(v);
}
__device__ __forceinline__ void updp(h2& s, h2& c, h2 cA, h2 sA, h2 GS, h2 GC){
  h2 e  = c*GS - s*GC;
  h2 s1 = s*cA + c*sA;
  h2 c1 = c*cA - s*sA;
  s = s1 + c1*e;
  c = c1 - s1*e;
}
__device__ __forceinline__ h2 splat2(_Float16 v){ h2 r; r[0]=v; r[1]=v; return r; }

#define NX4 1048576   // 4096*1024/4
#define NWA4 90112    // 352*1024/4

// ================ dispatch 1: convert ∪ phase+iter+factors ================
__global__ __launch_bounds__(256) void prep_k(const float* __restrict__ x,
    const float* __restrict__ wp, const float* __restrict__ wa,
    u16x4* __restrict__ xb, u16x4* __restrict__ wb, float* __restrict__ factors){
  __shared__ float ldsf[14336];       // 57,344 B: 2 bufs x (A 1024 + B 6144 f32)
  const int tid = threadIdx.x;
  const int bid = blockIdx.x;

  if (bid >= 256){
    // ---------- convert ----------
    int i = (bid - 256)*256 + tid;
    f32x4 v; u16x4* dst;
    if (i < NX4) { v = ((const f32x4*)x)[i]; dst = xb + i; }
    else { int j = i - NX4; v = ((const f32x4*)wa)[j]; dst = wb + j; }
    u16x4 r;
    r[0]=f2bf(v[0]); r[1]=f2bf(v[1]); r[2]=f2bf(v[2]); r[3]=f2bf(v[3]);
    *dst = r;
    return;
  }

  // ---------- phase block: rows [16*bid, 16*bid+16) ----------
  const int m0 = bid * 16;
  const int l  = tid & 63;
  const int w  = tid >> 6;
  const int rl = l & 15;
  const int q0 = l >> 4;

  // staging: rows of 256 B = 16 slots; LDS slot s of row r holds global slot
  // s ^ (r&15) (inverse-swizzled source, linear LDS dest, rule #21)
  const int tr = tid >> 4;
  const int ts = tid & 15;
  const int ss = ts ^ tr;
  const float* gx = x  + (size_t)(m0 + tr) * N_DIMS + ss*4;
  const float* gw = wp + (size_t)tr * N_DIMS + ss*4;

  #define PSTAGE(b, kt) { \
    gload16f(gx + (kt)*64, &ldsf[(b)*7168 + tid*4]); \
    _Pragma("unroll") \
    for (int i = 0; i < 6; i++) \
      gload16f(gw + (size_t)i*16384 + (kt)*64, &ldsf[(b)*7168 + 1024 + i*1024 + tid*4]); }

  f32x4 acc[3] = {};
  PSTAGE(0, 0)
  __syncthreads();

  const int s0 = (w & 1)*8 + q0*2;    // k-half by wave parity
  const int gb = (w >> 1) * 3;        // n-group base (0 or 3)

  for (int kt = 0; kt < 16; kt++){
    const int cb = kt & 1;
    if (kt < 15) PSTAGE(cb^1, kt+1)
    f32x4 a0 = *(const f32x4*)&ldsf[cb*7168 + rl*64 + ((s0     ^ rl) * 4)];
    f32x4 a1 = *(const f32x4*)&ldsf[cb*7168 + rl*64 + (((s0+1) ^ rl) * 4)];
    s16x8 af = mk8(a0, a1);
    #pragma unroll
    for (int ng = 0; ng < 3; ng++){
      const int rowb = (gb + ng)*16 + rl;
      f32x4 b0 = *(const f32x4*)&ldsf[cb*7168 + 1024 + rowb*64 + ((s0     ^ rl) * 4)];
      f32x4 b1 = *(const f32x4*)&ldsf[cb*7168 + 1024 + rowb*64 + (((s0+1) ^ rl) * 4)];
      acc[ng] = __builtin_amdgcn_mfma_f32_16x16x32_bf16(af, mk8(b0, b1), acc[ng], 0,0,0);
    }
    __syncthreads();
  }
  #undef PSTAGE

  // partial sums: red[w][ng][l] f32x4 at ldsf[0..3071]
  #pragma unroll
  for (int ng = 0; ng < 3; ng++)
    *(f32x4*)&ldsf[w*768 + ng*256 + l*4] = acc[ng];
  __syncthreads();

  // sum k-half pairs -> phases (revolutions) in phase_lds[16][96] at +4096
  if (!(w & 1)){
    #pragma unroll
    for (int ng = 0; ng < 3; ng++){
      const int G = gb + ng;
      f32x4 s = *(const f32x4*)&ldsf[ w   *768 + ng*256 + l*4]
              + *(const f32x4*)&ldsf[(w+1)*768 + ng*256 + l*4];
      #pragma unroll
      for (int rg = 0; rg < 4; rg++){
        const int row = q0*4 + rg;
        float t = s[rg] * INV2PI; t -= floorf(t);
        ldsf[4096 + row*96 + G*16 + rl] = t;
      }
    }
  }
  __syncthreads();

  // ---- v2 iter from LDS phases: row = w*4+q0, 16 lanes/row ----
  const int row16 = w*4 + q0;
  const int g = rl;
  const float* ph = &ldsf[4096 + row16*96];

  const h2 cAd = splat2((_Float16)0.99211470f), sAd = splat2((_Float16)0.12533323f);
  const h2 cAt = splat2((_Float16)0.92977649f), sAt = splat2((_Float16)0.36812455f);
  const h2 kd = splat2((_Float16)6.25e-4f);
  const h2 kt2 = splat2((_Float16)3.125e-4f);

  h2 sD, cD, sT[2], cT[2];
  {
    float d0 = ph[2*g], d1 = ph[2*g+1];
    float4 tw = *(const float4*)&ph[32 + 4*g];
    sD[0] = (_Float16)__builtin_amdgcn_sinf(d0);
    sD[1] = (_Float16)__builtin_amdgcn_sinf(d1);
    cD[0] = (_Float16)__builtin_amdgcn_cosf(d0);
    cD[1] = (_Float16)__builtin_amdgcn_cosf(d1);
    sT[0][0] = (_Float16)__builtin_amdgcn_sinf(tw.x); sT[0][1] = (_Float16)__builtin_amdgcn_sinf(tw.y);
    cT[0][0] = (_Float16)__builtin_amdgcn_cosf(tw.x); cT[0][1] = (_Float16)__builtin_amdgcn_cosf(tw.y);
    sT[1][0] = (_Float16)__builtin_amdgcn_sinf(tw.z); sT[1][1] = (_Float16)__builtin_amdgcn_sinf(tw.w);
    cT[1][0] = (_Float16)__builtin_amdgcn_cosf(tw.z); cT[1][1] = (_Float16)__builtin_amdgcn_cosf(tw.w);
  }

  h2 PD, PT;
  #define REDUCE { \
    h2 pd; pd[0] = sD[0]+sD[1]; pd[1] = cD[0]+cD[1]; \
    h2 ts_ = sT[0]+sT[1], tc_ = cT[0]+cT[1]; \
    h2 pt; pt[0] = ts_[0]+ts_[1]; pt[1] = tc_[0]+tc_[1]; \
    PD = rowsum16(pd); PT = rowsum16(pt); }

  REDUCE

  float Pth = 1.f, Pga = 1.f, mPth = 1.f, mPga = 1.f;
  for (int t = 0; t < 32; t++){
    h2 gd = PD * kd, gt = PT * kt2;
    h2 GSd = splat2(gd[0]), GCd = splat2(gd[1]);
    h2 GSt = splat2(gt[0]), GCt = splat2(gt[1]);
    updp(sD, cD, cAd, sAd, GSd, GCd);
    updp(sT[0], cT[0], cAt, sAt, GSt, GCt);
    updp(sT[1], cT[1], cAt, sAt, GSt, GCt);
    REDUCE
    float Sd = (float)PD[0], Cd = (float)PD[1];
    float St = (float)PT[0], Ct = (float)PT[1];
    float ft = 1.f + 0.003f * Cd * __builtin_amdgcn_rsqf(Cd*Cd + Sd*Sd);
    float fg = 1.f + 0.003f * Ct * __builtin_amdgcn_rsqf(Ct*Ct + St*St);
    Pth *= ft; mPth = fminf(mPth, Pth);
    Pga *= fg; mPga = fminf(mPga, Pga);
  }
  #undef REDUCE

  if (rl == 0){
    float4 f; f.x = Pth; f.y = EPSV * Pth / mPth; f.z = Pga; f.w = EPSV * Pga / mPga;
    *(float4*)(factors + (size_t)(m0 + row16)*4) = f;
  }
}

// ================ dispatch 2: amp GEMM + factor epilogue ================
// BM=64, BN=32 -> 704 blocks = 8 XCDs x (8 m-tiles x 11 n-tiles).
__global__ __launch_bounds__(256) void gemm_k(const u16* __restrict__ xb,
    const u16* __restrict__ wb, const float* __restrict__ factors,
    float* __restrict__ out){
  __shared__ u16 lds[2][6144];        // [buf][12 KB]: A 64x64, B 32x64
  const int tid = threadIdx.x;
  const int l   = tid & 63;
  const int w   = tid >> 6;

  const int bid = blockIdx.x;
  const int xcd = bid & 7;
  const int r   = bid >> 3;           // 0..87
  const int mt  = xcd * 8 + r / 11;
  const int nt  = r % 11;
  const int m0  = mt * 64;
  const int n0  = nt * 32;

  const int sr8  = l >> 3;
  const int scol = (((l & 7) ^ sr8) * 8);
  const u16* gA0 = xb + (size_t)(m0 + w*16 + sr8) * N_DIMS + scol;
  const u16* gB0 = wb + (size_t)(n0 + w*8  + sr8) * N_DIMS + scol;

  #define STAGE(b, kt) { \
    gload16(gA0 + (kt)*64,            &lds[b][w*1024]); \
    gload16(gA0 + (kt)*64 + 8*N_DIMS, &lds[b][w*1024 + 512]); \
    gload16(gB0 + (kt)*64,            &lds[b][4096 + w*512]); }

  const int rl = l & 15;
  const int q0 = l >> 4;
  const int sx = l & 7;
  const int wr = w >> 1, wc = w & 1;

  f32x4 acc[2] = {};
  STAGE(0, 0)
  __syncthreads();

  for (int kt = 0; kt < 16; kt++){
    const int cb = kt & 1;
    if (kt < 15) STAGE(cb^1, kt+1)
    s16x8 a[2][2], b[2];
    #pragma unroll
    for (int mi = 0; mi < 2; mi++)
    #pragma unroll
    for (int ks = 0; ks < 2; ks++){
      int off = (wr*32 + mi*16 + rl)*64 + (((ks*4 + q0) ^ sx) * 8);
      a[mi][ks] = *(const s16x8*)&lds[cb][off];
    }
    #pragma unroll
    for (int ks = 0; ks < 2; ks++){
      int off = 4096 + (wc*16 + rl)*64 + (((ks*4 + q0) ^ sx) * 8);
      b[ks] = *(const s16x8*)&lds[cb][off];
    }
    #pragma unroll
    for (int ks = 0; ks < 2; ks++)
    #pragma unroll
    for (int mi = 0; mi < 2; mi++)
      acc[mi] = __builtin_amdgcn_mfma_f32_16x16x32_bf16(a[mi][ks], b[ks], acc[mi], 0,0,0);
    __syncthreads();
  }
  #undef STAGE

  // epilogue: class per n-tile (0: delta f=1; 1-2: theta; 3-10: gamma)
  const int n = n0 + wc*16 + rl;
  const int cls = (nt == 0) ? 0 : ((nt < 3) ? 1 : 2);
  #pragma unroll
  for (int mi = 0; mi < 2; mi++)
  #pragma unroll
  for (int rg = 0; rg < 4; rg++){
    const int m = m0 + wr*32 + mi*16 + q0*4 + rg;
    float a0 = fmaxf(fabsf(acc[mi][rg]), EPSV);
    float o = a0;
    if (cls != 0){
      const float2 f = *(const float2*)(factors + (size_t)m*4 + ((cls == 2) ? 2 : 0));
      o = fmaxf(a0 * f.x, f.y);
    }
    out[(size_t)m * N_OSC + n] = o;
  }
}

// ---------------- launch ----------------
extern "C" void kernel_launch(void* const* d_in, const int* in_sizes, int n_in,
                              void* d_out, int out_size, void* d_ws, size_t ws_size,
                              hipStream_t stream){
  const float* x  = (const float*)d_in[0];
  const float* wp = (const float*)d_in[1];
  const float* wa = (const float*)d_in[2];
  float* out = (float*)d_out;
  char* ws = (char*)d_ws;
  u16* xb  = (u16*)(ws);                    // 8,388,608 B
  u16* wb  = (u16*)(ws + 8388608);          //   720,896 B (W_amp only)
  float* factors = (float*)(ws + 9109504);  //    65,536 B (4096 x float4)

  // 256 phase blocks (scheduled first) + 4448 convert blocks
  prep_k<<<4704, 256, 0, stream>>>(x, wp, wa, (u16x4*)xb, (u16x4*)wb, factors);
  gemm_k<<<704, 256, 0, stream>>>(xb, wb, factors, out);
}

// Round 18
// 31.327 us; speedup vs baseline: 1.1142x; 1.1142x over previous
//
#include <hip/hip_runtime.h>

typedef float  f32x4 __attribute__((ext_vector_type(4)));
typedef short  s16x8 __attribute__((ext_vector_type(8)));
typedef _Float16 h2 __attribute__((ext_vector_type(2)));
typedef unsigned short u16;
typedef u16 u16x4 __attribute__((ext_vector_type(4)));

#define N_DIMS 1024
#define N_OSC  352
#define N_PH   96            // only delta(32)+theta(64) phases are live
#define BATCH  4096
#define EPSV   1e-6f
#define INV2PI 0.15915494309189535f

__device__ __forceinline__ u16 f2bf(float f){
  unsigned u = __builtin_bit_cast(unsigned, f);
  u += 0x7FFFu + ((u >> 16) & 1u);   // round-to-nearest-even
  return (u16)(u >> 16);
}
__device__ __forceinline__ float bf2f(unsigned h){
  return __builtin_bit_cast(float, h << 16);
}

#define NX4 1048576   // 4096*1024/4
#define NWP4 24576    // 96*1024/4  (live W_phase rows)
#define NWA4 90112    // 352*1024/4
#define NCONV (NX4 + NWP4 + NWA4)   // 1,163,264

// wb[448][1024] = W_phase rows 0..95, then W_amp rows 0..351
__global__ __launch_bounds__(256) void convert_k(const f32x4* __restrict__ x,
    const f32x4* __restrict__ wp, const f32x4* __restrict__ wa,
    u16x4* __restrict__ xb, u16x4* __restrict__ wb){
  int i = blockIdx.x * 256 + threadIdx.x;
  if (i >= NCONV) return;
  f32x4 v; u16x4* dst;
  if (i < NX4) { v = x[i]; dst = xb + i; }
  else {
    int j = i - NX4;
    v = (j < NWP4) ? wp[j] : wa[j - NWP4];
    dst = wb + j;
  }
  u16x4 r;
  r[0]=f2bf(v[0]); r[1]=f2bf(v[1]); r[2]=f2bf(v[2]); r[3]=f2bf(v[3]);
  *dst = r;
}

// ---------------- GEMM: [phase0[4096][96] | amp0[4096][352]] = x @ wb^T ----------------
// BM=64, BN=32, BK=64 -> 64 x 14 = 896 blocks (3.5/CU; 24 KB LDS -> 6/CU capacity).
// 4 waves (2m x 2n), wave tile 32x16 via 16x16x32 MFMA acc[2].
// global_load_lds w=16 staging, T2 swizzle via inverse-swizzled source.
// XCD-bijective: 896 = 8 XCDs x (8 m-tiles x 14 n-tiles).
__device__ __forceinline__ void gload16(const u16* g, u16* l){
  __builtin_amdgcn_global_load_lds(
      (const __attribute__((address_space(1))) unsigned int*)(g),
      (__attribute__((address_space(3))) unsigned int*)(l), 16, 0, 0);
}

__global__ __launch_bounds__(256) void gemm_k(const u16* __restrict__ xb,
    const u16* __restrict__ wb, u16* __restrict__ phase0, float* __restrict__ amp0){
  __shared__ u16 lds[2][6144];          // [buf][12 KB]: A 64x64 at 0, B 32x64 at u16 4096
  const int tid = threadIdx.x;
  const int l   = tid & 63;
  const int w   = tid >> 6;

  const int bid = blockIdx.x;
  const int xcd = bid & 7;
  const int r   = bid >> 3;             // 0..111 within this XCD
  const int mt  = xcd * 8 + r / 14;     // 8 contiguous m-tiles per XCD
  const int nt  = r % 14;
  const int m0  = mt * 64;
  const int n0  = nt * 32;

  // staging: A rows w*16..+15 (2 issues of 8 rows), B rows w*8..+7 (1 issue)
  const int sr8  = l >> 3;
  const int scol = (((l & 7) ^ sr8) * 8);           // inverse-swizzled k-slot
  const u16* ga = xb + (size_t)(m0 + w*16 + sr8) * N_DIMS + scol;
  const u16* gb = wb + (size_t)(n0 + w*8  + sr8) * N_DIMS + scol;

  #define STAGE(b, kt) { \
    gload16(ga + (kt)*64,            &lds[b][w*1024]); \
    gload16(ga + (kt)*64 + 8*N_DIMS, &lds[b][w*1024 + 512]); \
    gload16(gb + (kt)*64,            &lds[b][4096 + w*512]); }

  const int rl = l & 15;
  const int q0 = l >> 4;
  const int sx = l & 7;                 // row&7 for frag rows (A and B alike)
  const int wr = w >> 1, wc = w & 1;

  f32x4 acc[2] = {};
  STAGE(0, 0)
  __syncthreads();

  for (int kt = 0; kt < 16; kt++){
    const int cb = kt & 1;
    if (kt < 15) STAGE(cb^1, kt+1)
    s16x8 a[2][2], b[2];
    #pragma unroll
    for (int mi = 0; mi < 2; mi++)
    #pragma unroll
    for (int ks = 0; ks < 2; ks++){
      int off = (wr*32 + mi*16 + rl)*64 + (((ks*4 + q0) ^ sx) * 8);
      a[mi][ks] = *(const s16x8*)&lds[cb][off];
    }
    #pragma unroll
    for (int ks = 0; ks < 2; ks++){
      int off = 4096 + (wc*16 + rl)*64 + (((ks*4 + q0) ^ sx) * 8);
      b[ks] = *(const s16x8*)&lds[cb][off];
    }
    #pragma unroll
    for (int ks = 0; ks < 2; ks++)
    #pragma unroll
    for (int mi = 0; mi < 2; mi++)
      acc[mi] = __builtin_amdgcn_mfma_f32_16x16x32_bf16(a[mi][ks], b[ks], acc[mi], 0,0,0);
    __syncthreads();
  }
  #undef STAGE

  // C/D layout: col = lane&15, row = (lane>>4)*4 + reg.
  // n-block of 32 is uniformly phase (n0<96) or amp (96 = 3*32).
  const int n = n0 + wc*16 + rl;
  const bool isph = (n < N_PH);
  #pragma unroll
  for (int mi = 0; mi < 2; mi++)
  #pragma unroll
  for (int rg = 0; rg < 4; rg++){
    const int m = m0 + wr*32 + mi*16 + q0*4 + rg;
    float v = acc[mi][rg];
    if (isph){ float t = v * INV2PI; t -= floorf(t); phase0[(size_t)m*N_PH + n] = f2bf(t); }
    else     { amp0[(size_t)m*N_OSC + (n - N_PH)] = fmaxf(fabsf(v), EPSV); }
  }
}

// ---------------- iteration: delta+theta only ----------------
__device__ __forceinline__ int ibc(h2 v){ return __builtin_bit_cast(int, v); }
__device__ __forceinline__ h2  hbc(int v){ return __builtin_bit_cast(h2, v); }

__device__ __forceinline__ h2 rowsum16(h2 x){
  int v = ibc(x);
  v = ibc(hbc(v) + hbc(__builtin_amdgcn_mov_dpp(v, 0x121, 0xF, 0xF, true))); // row_ror:1
  v = ibc(hbc(v) + hbc(__builtin_amdgcn_mov_dpp(v, 0x122, 0xF, 0xF, true))); // row_ror:2
  v = ibc(hbc(v) + hbc(__builtin_amdgcn_mov_dpp(v, 0x124, 0xF, 0xF, true))); // row_ror:4
  v = ibc(hbc(v) + hbc(__builtin_amdgcn_mov_dpp(v, 0x128, 0xF, 0xF, true))); // row_ror:8
  return hbc(v);
}

__device__ __forceinline__ void updp(h2& s, h2& c, h2 cA, h2 sA, h2 GS, h2 GC){
  h2 e  = c*GS - s*GC;        // eps (radians), |e| <= 0.02
  h2 s1 = s*cA + c*sA;
  h2 c1 = c*cA - s*sA;
  s = s1 + c1*e;
  c = c1 - s1*e;
}

__device__ __forceinline__ h2 splat2(_Float16 v){ h2 r; r[0]=v; r[1]=v; return r; }

__global__ __launch_bounds__(256) void iter_k(const u16* __restrict__ phase0,
                                              float* __restrict__ amp){
  const int tid = threadIdx.x;
  const int l   = tid & 63;
  const int g   = l & 15;
  const int row = blockIdx.x*16 + (tid>>6)*4 + (l>>4);
  const size_t rb  = (size_t)row * N_OSC;   // amp row base
  const size_t rbp = (size_t)row * N_PH;    // phase row base

  const h2 cAd = splat2((_Float16)0.99211470f), sAd = splat2((_Float16)0.12533323f);
  const h2 cAt = splat2((_Float16)0.92977649f), sAt = splat2((_Float16)0.36812455f);
  const h2 kd = splat2((_Float16)6.25e-4f);    // DT*COUPLING/32
  const h2 kt = splat2((_Float16)3.125e-4f);   // /64

  h2 sD, cD, sT[2], cT[2];
  {
    const u16* pr = phase0 + rbp;
    unsigned dw = *(const unsigned*)(pr + 2*g);     // 2 bf16 (delta)
    uint2 tw    = *(const uint2*)(pr + 32 + 4*g);   // 4 bf16 (theta)
    #define SC2(dS, dC, i, p0, p1) { \
      dS[i][0] = (_Float16)__builtin_amdgcn_sinf(p0); \
      dS[i][1] = (_Float16)__builtin_amdgcn_sinf(p1); \
      dC[i][0] = (_Float16)__builtin_amdgcn_cosf(p0); \
      dC[i][1] = (_Float16)__builtin_amdgcn_cosf(p1); }
    {
      float d0 = bf2f(dw & 0xFFFFu), d1 = bf2f(dw >> 16);
      sD[0] = (_Float16)__builtin_amdgcn_sinf(d0);
      sD[1] = (_Float16)__builtin_amdgcn_sinf(d1);
      cD[0] = (_Float16)__builtin_amdgcn_cosf(d0);
      cD[1] = (_Float16)__builtin_amdgcn_cosf(d1);
    }
    SC2(sT, cT, 0, bf2f(tw.x & 0xFFFFu), bf2f(tw.x >> 16))
    SC2(sT, cT, 1, bf2f(tw.y & 0xFFFFu), bf2f(tw.y >> 16))
    #undef SC2
  }

  h2 PD, PT;
  #define REDUCE { \
    h2 pd; pd[0] = sD[0]+sD[1]; pd[1] = cD[0]+cD[1]; \
    h2 ts = sT[0]+sT[1], tc = cT[0]+cT[1]; \
    h2 pt; pt[0] = ts[0]+ts[1]; pt[1] = tc[0]+tc[1]; \
    PD = rowsum16(pd); PT = rowsum16(pt); }

  REDUCE

  float Pth = 1.f, Pga = 1.f, mPth = 1.f, mPga = 1.f;
  for (int t = 0; t < 32; t++){
    h2 gd = PD * kd, gt = PT * kt;      // (k*S, k*C)
    h2 GSd = splat2(gd[0]), GCd = splat2(gd[1]);
    h2 GSt = splat2(gt[0]), GCt = splat2(gt[1]);
    updp(sD, cD, cAd, sAd, GSd, GCd);
    updp(sT[0], cT[0], cAt, sAt, GSt, GCt);
    updp(sT[1], cT[1], cAt, sAt, GSt, GCt);
    REDUCE
    float Sd = (float)PD[0], Cd = (float)PD[1];
    float St = (float)PT[0], Ct = (float)PT[1];
    float ft = 1.f + 0.003f * Cd * __builtin_amdgcn_rsqf(Cd*Cd + Sd*Sd);
    float fg = 1.f + 0.003f * Ct * __builtin_amdgcn_rsqf(Ct*Ct + St*St);
    Pth *= ft; mPth = fminf(mPth, Pth);
    Pga *= fg; mPga = fminf(mPga, Pga);
  }
  #undef REDUCE

  const float cth = EPSV * Pth / mPth;
  const float cga = EPSV * Pga / mPga;
  {
    float4 a = *(const float4*)(amp + rb + 32 + 4*g);
    a.x = fmaxf(a.x*Pth, cth); a.y = fmaxf(a.y*Pth, cth);
    a.z = fmaxf(a.z*Pth, cth); a.w = fmaxf(a.w*Pth, cth);
    *(float4*)(amp + rb + 32 + 4*g) = a;
  }
  #pragma unroll
  for (int i = 0; i < 4; i++){
    float4 a = *(const float4*)(amp + rb + 96 + 16*g + 4*i);
    a.x = fmaxf(a.x*Pga, cga); a.y = fmaxf(a.y*Pga, cga);
    a.z = fmaxf(a.z*Pga, cga); a.w = fmaxf(a.w*Pga, cga);
    *(float4*)(amp + rb + 96 + 16*g + 4*i) = a;
  }
  // delta amps (factor 1): already final, written by gemm_k
}

// ---------------- launch ----------------
extern "C" void kernel_launch(void* const* d_in, const int* in_sizes, int n_in,
                              void* d_out, int out_size, void* d_ws, size_t ws_size,
                              hipStream_t stream){
  const float* x  = (const float*)d_in[0];
  const float* wp = (const float*)d_in[1];
  const float* wa = (const float*)d_in[2];
  float* out = (float*)d_out;
  char* ws = (char*)d_ws;
  u16* xb  = (u16*)(ws);                    // 8,388,608 B
  u16* wb  = (u16*)(ws + 8388608);          //   917,504 B (448 rows)
  u16* phase0 = (u16*)(ws + 9306112);       //   786,432 B (bf16, [4096][96])

  convert_k<<<4544, 256, 0, stream>>>((const f32x4*)x, (const f32x4*)wp, (const f32x4*)wa,
                                      (u16x4*)xb, (u16x4*)wb);
  gemm_k<<<896, 256, 0, stream>>>(xb, wb, phase0, out);
  iter_k<<<256, 256, 0, stream>>>(phase0, out);
}